// Round 5
// baseline (9887.540 us; speedup 1.0000x reference)
//
#include <hip/hip_runtime.h>

#define N      4096
#define NBLK   256
#define NTHR   1024
#define RPB    16           // rows per block  (N / NBLK)
#define R      4            // rows per wave
#define NCK    4            // j-chunks per row (waves sharing a row-group)
#define CHUNK  (N / NCK)    // 1024 columns per chunk
#define TPL    (CHUNK / 64) // 16 elements per lane per row

#define LOG2E 1.4426950408889634f

// Static device scratch (~164 KB). NOT d_ws (rounds 1-2: unvalidated ws_size
// => OOB write => GPU fault). NOT cooperative launch (rounds 0,4: grid.sync
// under graph capture => hang => dead container). Persistent kernel + hand
// rolled device-scope barrier instead.
struct WS {
  float4 xpack[N];   // x0,x1,x2, |x|^2
  float4 ypack[N];   // y0,y1,y2, |y|^2
  float  fs[N];      // (f/eps + log_u) * log2e  (transformed potential, rows=x)
  float  gs[N];      // (g/eps + log_u) * log2e  (transformed potential, rows=y)
  double accC;       // sum of all pairwise distances (for eps)
  double accE;       // final EMD accumulator
};
__device__ WS g_ws;

// barrier state — reset by k_init every call (globals persist across replays)
__device__ unsigned g_arrive[NBLK];
__device__ unsigned g_release;
__device__ unsigned g_dead;

#define AL(p)    __hip_atomic_load((p),  __ATOMIC_RELAXED, __HIP_MEMORY_SCOPE_AGENT)
#define AS(p,v)  __hip_atomic_store((p),(v), __ATOMIC_RELAXED, __HIP_MEMORY_SCOPE_AGENT)
#define SPIN_MAX 2000000u   // bounded spin: broken barrier => wrong answer, not hang

__device__ __forceinline__ float ex2f(float v) { return __builtin_amdgcn_exp2f(v); }

// Device-scope grid barrier (sense = monotonically increasing epoch k).
// __syncthreads() before arrive drains the whole block's stores to L2
// (compiler emits vmcnt(0) before s_barrier); __threadfence() does the
// agent-scope L2 writeback/invalidate for cross-XCD visibility.
__device__ __forceinline__ void gbar(unsigned k) {
  const int tid = threadIdx.x, bid = blockIdx.x;
  __syncthreads();
  if (tid == 0) { __threadfence(); AS(&g_arrive[bid], k); }
  if (bid == 0) {
    if (tid < NBLK) {
      unsigned t = 0;
      while (AL(&g_arrive[tid]) < k) {
        if (AL(&g_dead)) break;
        if (++t > SPIN_MAX) { AS(&g_dead, 1u); break; }
        __builtin_amdgcn_s_sleep(2);
      }
    }
    __syncthreads();
    if (tid == 0) AS(&g_release, k);
  } else if (tid == 0) {
    unsigned t = 0;
    while (AL(&g_release) < k) {
      if (AL(&g_dead)) break;
      if (++t > SPIN_MAX) { AS(&g_dead, 1u); break; }
      __builtin_amdgcn_s_sleep(2);
    }
  }
  if (tid == 0) __threadfence();
  __syncthreads();
}

// ---------------------------------------------------------------------------
// One logsumexp half-pass, previous-potential offset (single exp/element):
//   e = potIn[j] + nie2*C_ij + (12 + potRow_prev[i]);  Sigma = sum 2^e
//   potRow_new[i] = potRow_prev[i] - log2(Sigma)
// Exponents stay centered near 0 once converging; first-iteration range
// ~[-330,-17] — flushed terms are < 2^-100 relative. No overflow possible.
__device__ void lse_pass(const float4* __restrict__ rowPack,
                         const float4* __restrict__ colPack,
                         const float*  __restrict__ potIn,
                         float*        __restrict__ potRow,  // old in, new out
                         int rowBase, float nie2, float* part)
{
  const int tid  = threadIdx.x;
  const int lane = tid & 63;
  const int wid  = tid >> 6;   // 0..15
  const int rg   = wid >> 2;   // row-group 0..3
  const int ck   = wid & 3;    // chunk 0..3
  const int r0   = rowBase + rg * R;

  float c0[R], c1[R], c2[R], ca[R], F[R], l[R];
#pragma unroll
  for (int r = 0; r < R; ++r) {
    float4 p = rowPack[r0 + r];
    c0[r] = -2.f * p.x; c1[r] = -2.f * p.y; c2[r] = -2.f * p.z; ca[r] = p.w;
    F[r] = 12.0f + potRow[r0 + r];
    l[r] = 0.f;
  }

  int j = ck * CHUNK + lane;
#pragma unroll 4
  for (int t = 0; t < TPL; ++t, j += 64) {
    float4 q = colPack[j];
    float  pj = potIn[j];
    float  b  = q.w;
#pragma unroll
    for (int r = 0; r < R; ++r) {
      float d2 = fmaf(c0[r], q.x, fmaf(c1[r], q.y, fmaf(c2[r], q.z, ca[r] + b)));
      float c  = __builtin_amdgcn_sqrtf(fmaxf(d2, 1e-12f));   // C_ij
      float e  = fmaf(nie2, c, pj + F[r]);                    // base-2 exponent
      l[r] += ex2f(e);
    }
  }

  // wave-level butterfly sum (row offset is uniform -> plain adds)
#pragma unroll
  for (int r = 0; r < R; ++r) {
#pragma unroll
    for (int off = 32; off; off >>= 1) l[r] += __shfl_xor(l[r], off);
  }

  if (lane == 0) {
#pragma unroll
    for (int r = 0; r < R; ++r) part[(rg * R + r) * NCK + ck] = l[r];
  }
  __syncthreads();

  if (tid < RPB) {   // one thread per row: merge 4 chunk partials
    float S = part[tid * NCK + 0] + part[tid * NCK + 1]
            + part[tid * NCK + 2] + part[tid * NCK + 3];
    int row = rowBase + tid;
    potRow[row] = potRow[row] - __builtin_amdgcn_logf(S);  // v_log_f32 = log2
  }
  __syncthreads();   // protect `part` before any reuse (caller also gbar()s)
}

// ---------------------------------------------------------------------------
// Full-pair accumulation. emd==0: accC += sum C_ij.
// emd==1: accE += sum 2^(fs_i+gs_j+nie2*C_ij) * C_ij.
__device__ void pair_sum(int rowBase, int emd, float nie2, double* ldsd)
{
  const int tid  = threadIdx.x;
  const int lane = tid & 63;
  const int wid  = tid >> 6;
  const int rg   = wid >> 2;
  const int ck   = wid & 3;
  const int r0   = rowBase + rg * R;

  float c0[R], c1[R], c2[R], ca[R], fr[R];
  double acc[R];
#pragma unroll
  for (int r = 0; r < R; ++r) {
    float4 p = g_ws.xpack[r0 + r];
    c0[r] = -2.f * p.x; c1[r] = -2.f * p.y; c2[r] = -2.f * p.z; ca[r] = p.w;
    fr[r] = emd ? g_ws.fs[r0 + r] : 0.f;
    acc[r] = 0.0;
  }

  int j = ck * CHUNK + lane;
  for (int t = 0; t < TPL; ++t, j += 64) {
    float4 q = g_ws.ypack[j];
    float  pj = emd ? g_ws.gs[j] : 0.f;
    float  b  = q.w;
#pragma unroll
    for (int r = 0; r < R; ++r) {
      float d2 = fmaf(c0[r], q.x, fmaf(c1[r], q.y, fmaf(c2[r], q.z, ca[r] + b)));
      float c = __builtin_amdgcn_sqrtf(fmaxf(d2, 1e-12f));
      float term = emd ? ex2f(fmaf(nie2, c, fr[r] + pj)) * c : c;
      acc[r] += (double)term;
    }
  }

  double a = (acc[0] + acc[1]) + (acc[2] + acc[3]);
#pragma unroll
  for (int off = 32; off; off >>= 1) a += __shfl_xor(a, off);
  if (lane == 0) ldsd[wid] = a;
  __syncthreads();
  if (tid == 0) {
    double s = 0.0;
#pragma unroll
    for (int w = 0; w < 16; ++w) s += ldsd[w];
    atomicAdd(emd ? &g_ws.accE : &g_ws.accC, s);
  }
  __syncthreads();
}

// ---------------------------------------------------------------------------
// reset barrier/accumulator state (device globals persist across graph replays)
__global__ void k_init()
{
  int i = threadIdx.x;
  if (i < NBLK) g_arrive[i] = 0u;
  if (i == 0) { g_release = 0u; g_dead = 0u; g_ws.accC = 0.0; g_ws.accE = 0.0; }
}

// ---------------------------------------------------------------------------
extern "C" __global__ void __launch_bounds__(NTHR)
emd_all(const float* __restrict__ x, const float* __restrict__ y,
        float* __restrict__ out)
{
  __shared__ float  part[RPB * NCK];
  __shared__ double ldsd[16];

  const int tid = threadIdx.x;
  const int bid = blockIdx.x;
  const int gt  = bid * NTHR + tid;
  const int rowBase = bid * RPB;
  unsigned k = 1;

  // pack points (blocks 0..3), init transformed potentials (f=g=0 -> -12)
  if (gt < N) {
    float a0 = x[gt * 3 + 0], a1 = x[gt * 3 + 1], a2 = x[gt * 3 + 2];
    g_ws.xpack[gt] = make_float4(a0, a1, a2, fmaf(a0, a0, fmaf(a1, a1, a2 * a2)));
    float b0 = y[gt * 3 + 0], b1 = y[gt * 3 + 1], b2 = y[gt * 3 + 2];
    g_ws.ypack[gt] = make_float4(b0, b1, b2, fmaf(b0, b0, fmaf(b1, b1, b2 * b2)));
    g_ws.fs[gt] = -12.0f;
    g_ws.gs[gt] = -12.0f;
  }
  gbar(k++);

  // eps = 0.02 * mean(C)
  pair_sum(rowBase, 0, 0.f, ldsd);
  gbar(k++);
  const float nie2 = -LOG2E /
      (float)(0.02 * g_ws.accC / ((double)N * (double)N));

  // 300 Gauss-Seidel Sinkhorn iterations
  for (int it = 0; it < 300; ++it) {
    lse_pass(g_ws.xpack, g_ws.ypack, g_ws.gs, g_ws.fs, rowBase, nie2, part);
    gbar(k++);
    lse_pass(g_ws.ypack, g_ws.xpack, g_ws.fs, g_ws.gs, rowBase, nie2, part);
    gbar(k++);
  }

  // EMD = sum_ij 2^(fs_i+gs_j+nie2*C_ij) * C_ij
  pair_sum(rowBase, 1, nie2, ldsd);
  gbar(k++);
  if (gt == 0) out[0] = (float)g_ws.accE;
}

extern "C" void kernel_launch(void* const* d_in, const int* in_sizes, int n_in,
                              void* d_out, int out_size, void* d_ws, size_t ws_size,
                              hipStream_t stream) {
  const float* x = (const float*)d_in[0];
  const float* y = (const float*)d_in[1];
  float* out = (float*)d_out;
  (void)d_ws; (void)ws_size;

  k_init<<<dim3(1), dim3(NBLK), 0, stream>>>();
  emd_all<<<dim3(NBLK), dim3(NTHR), 0, stream>>>(x, y, out);
}

// Round 6
// 6144.740 us; speedup vs baseline: 1.6091x; 1.6091x over previous
//
#include <hip/hip_runtime.h>

#define N      4096
#define NBLK   256
#define NTHR   1024
#define RPB    16           // rows per block  (N / NBLK)
#define R      4            // rows per wave
#define NCK    4            // j-chunks per row (waves sharing a row-group)
#define CHUNK  (N / NCK)    // 1024 columns per chunk
#define TPL    (CHUNK / 64) // 16 elements per lane per row

#define LOG2E 1.4426950408889634f

// Static device scratch. NOT d_ws (rounds 1-2: unvalidated ws_size => OOB
// fault). NOT cooperative launch (rounds 0,4: grid.sync under graph capture
// => hang). Round 5 lesson: __threadfence() = full L2 writeback+invalidate
// per barrier (FETCH_SIZE 48MB = 600x80KB refetch, VALUBusy 33%) — so this
// version uses NO fences at all:
//  * xpack/ypack: written redundantly by EVERY block (identical values) so
//    each XCD L2 owns a full correct copy; plain cached reads.
//  * fs/gs + accums: agent-scope relaxed atomics only (IF$-coherent per
//    access, no L2 allocation => no staleness, no flush needed).
struct WS {
  float4 xpack[N];   // x0,x1,x2, |x|^2   (per-XCD redundant copies)
  float4 ypack[N];   // y0,y1,y2, |y|^2
  float  fs[N];      // (f/eps + log_u) * log2e   — coherent access only
  float  gs[N];      // (g/eps + log_u) * log2e   — coherent access only
  double accC;       // sum of all pairwise distances (for eps)
  double accE;       // final EMD accumulator
};
__device__ WS g_ws;

// barrier state — reset by k_init every call (globals persist across replays)
__device__ unsigned g_arrive[NBLK];
__device__ unsigned g_release;
__device__ unsigned g_dead;

#define AL(p)   __hip_atomic_load((p),  __ATOMIC_RELAXED, __HIP_MEMORY_SCOPE_AGENT)
#define AS(p,v) __hip_atomic_store((p),(v), __ATOMIC_RELAXED, __HIP_MEMORY_SCOPE_AGENT)
#define SPIN_MAX 4000000u   // bounded spin: broken barrier => wrong answer, not hang

__device__ __forceinline__ float  cload (const float*  p){ return __hip_atomic_load(p, __ATOMIC_RELAXED, __HIP_MEMORY_SCOPE_AGENT); }
__device__ __forceinline__ void   cstore(float* p, float v){ __hip_atomic_store(p, v, __ATOMIC_RELAXED, __HIP_MEMORY_SCOPE_AGENT); }
__device__ __forceinline__ double cloadd(const double* p){ return __hip_atomic_load(p, __ATOMIC_RELAXED, __HIP_MEMORY_SCOPE_AGENT); }
__device__ __forceinline__ float  ex2f(float v) { return __builtin_amdgcn_exp2f(v); }

// Device-scope grid barrier, FENCE-FREE. All cross-block data moves through
// IF$-coherent atomics; __syncthreads() before arrive drains vmcnt(0), so
// those stores are globally visible before the flag is set.
__device__ __forceinline__ void gbar(unsigned k) {
  __syncthreads();
  if (threadIdx.x == 0) AS(&g_arrive[blockIdx.x], k);
  if (blockIdx.x == 0) {
    if (threadIdx.x < NBLK) {
      unsigned t = 0;
      while (AL(&g_arrive[threadIdx.x]) < k) {
        if (AL(&g_dead)) break;
        if (++t > SPIN_MAX) { AS(&g_dead, 1u); break; }
        __builtin_amdgcn_s_sleep(1);
      }
    }
    __syncthreads();
    if (threadIdx.x == 0) AS(&g_release, k);
  } else if (threadIdx.x == 0) {
    unsigned t = 0;
    while (AL(&g_release) < k) {
      if (AL(&g_dead)) break;
      if (++t > SPIN_MAX) { AS(&g_dead, 1u); break; }
      __builtin_amdgcn_s_sleep(2);
    }
  }
  __syncthreads();
}

// ---------------------------------------------------------------------------
// One logsumexp half-pass, previous-potential offset (single exp/element):
//   e = potIn[j] + nie2*C_ij + (12 + potRow_prev[i]);  Sigma = sum 2^e
//   potRow_new[i] = potRow_prev[i] - log2(Sigma)       (exact for any prev)
__device__ void lse_pass(const float4* __restrict__ rowPack,
                         const float4* __restrict__ colPack,
                         const float*  __restrict__ potIn,
                         float*        __restrict__ potRow,  // old in, new out
                         int rowBase, float nie2, float* part)
{
  const int tid  = threadIdx.x;
  const int lane = tid & 63;
  const int wid  = tid >> 6;   // 0..15
  const int rg   = wid >> 2;   // row-group 0..3
  const int ck   = wid & 3;    // chunk 0..3
  const int r0   = rowBase + rg * R;
  const int j0   = ck * CHUNK + lane;

  // prefetch this wave's 16 potIn values (coherent, 16 loads in flight ->
  // one IF$-latency stall per pass, hidden across 4 waves/SIMD)
  float pj[TPL];
#pragma unroll
  for (int t = 0; t < TPL; ++t) pj[t] = cload(&potIn[j0 + t * 64]);

  float c0[R], c1[R], c2[R], ca[R], F[R], l[R];
#pragma unroll
  for (int r = 0; r < R; ++r) {
    float4 p = rowPack[r0 + r];          // plain cached (per-XCD L2 copy)
    c0[r] = -2.f * p.x; c1[r] = -2.f * p.y; c2[r] = -2.f * p.z; ca[r] = p.w;
    F[r] = 12.0f + cload(&potRow[r0 + r]);
    l[r] = 0.f;
  }

#pragma unroll           // FULL unroll: pj[] must stay in VGPRs
  for (int t = 0; t < TPL; ++t) {
    float4 q = colPack[j0 + t * 64];     // plain cached
    float  b = q.w;
#pragma unroll
    for (int r = 0; r < R; ++r) {
      float d2 = fmaf(c0[r], q.x, fmaf(c1[r], q.y, fmaf(c2[r], q.z, ca[r] + b)));
      float c  = __builtin_amdgcn_sqrtf(fmaxf(d2, 1e-12f));   // C_ij
      float e  = fmaf(nie2, c, pj[t] + F[r]);                 // base-2 exponent
      l[r] += ex2f(e);
    }
  }

  // wave-level butterfly sum (row offset is uniform -> plain adds)
#pragma unroll
  for (int r = 0; r < R; ++r) {
#pragma unroll
    for (int off = 32; off; off >>= 1) l[r] += __shfl_xor(l[r], off);
  }

  if (lane == 0) {
#pragma unroll
    for (int r = 0; r < R; ++r) part[(rg * R + r) * NCK + ck] = l[r];
  }
  __syncthreads();

  if (tid < RPB) {   // one thread per row: merge 4 chunk partials
    float S = part[tid * NCK + 0] + part[tid * NCK + 1]
            + part[tid * NCK + 2] + part[tid * NCK + 3];
    int row = rowBase + tid;
    cstore(&potRow[row], cload(&potRow[row]) - __builtin_amdgcn_logf(S));
  }
  __syncthreads();   // protect `part` before reuse
}

// ---------------------------------------------------------------------------
// Full-pair accumulation. emd==0: accC += sum C_ij.
// emd==1: accE += sum 2^(fs_i+gs_j+nie2*C_ij) * C_ij.
__device__ void pair_sum(int rowBase, int emd, float nie2, double* ldsd)
{
  const int tid  = threadIdx.x;
  const int lane = tid & 63;
  const int wid  = tid >> 6;
  const int rg   = wid >> 2;
  const int ck   = wid & 3;
  const int r0   = rowBase + rg * R;
  const int j0   = ck * CHUNK + lane;

  float pj[TPL];
#pragma unroll
  for (int t = 0; t < TPL; ++t) pj[t] = emd ? cload(&g_ws.gs[j0 + t * 64]) : 0.f;

  float c0[R], c1[R], c2[R], ca[R], fr[R];
  double acc[R];
#pragma unroll
  for (int r = 0; r < R; ++r) {
    float4 p = g_ws.xpack[r0 + r];
    c0[r] = -2.f * p.x; c1[r] = -2.f * p.y; c2[r] = -2.f * p.z; ca[r] = p.w;
    fr[r] = emd ? cload(&g_ws.fs[r0 + r]) : 0.f;
    acc[r] = 0.0;
  }

#pragma unroll
  for (int t = 0; t < TPL; ++t) {
    float4 q = g_ws.ypack[j0 + t * 64];
    float  b = q.w;
#pragma unroll
    for (int r = 0; r < R; ++r) {
      float d2 = fmaf(c0[r], q.x, fmaf(c1[r], q.y, fmaf(c2[r], q.z, ca[r] + b)));
      float c = __builtin_amdgcn_sqrtf(fmaxf(d2, 1e-12f));
      float term = emd ? ex2f(fmaf(nie2, c, fr[r] + pj[t])) * c : c;
      acc[r] += (double)term;
    }
  }

  double a = (acc[0] + acc[1]) + (acc[2] + acc[3]);
#pragma unroll
  for (int off = 32; off; off >>= 1) a += __shfl_xor(a, off);
  if (lane == 0) ldsd[wid] = a;
  __syncthreads();
  if (tid == 0) {
    double s = 0.0;
#pragma unroll
    for (int w = 0; w < 16; ++w) s += ldsd[w];
    atomicAdd(emd ? &g_ws.accE : &g_ws.accC, s);   // device-scope, IF$-coherent
  }
  __syncthreads();
}

// ---------------------------------------------------------------------------
// reset barrier/accumulator state (device globals persist across graph replays)
__global__ void k_init()
{
  int i = threadIdx.x;
  if (i < NBLK) g_arrive[i] = 0u;
  if (i == 0) { g_release = 0u; g_dead = 0u; g_ws.accC = 0.0; g_ws.accE = 0.0; }
}

// ---------------------------------------------------------------------------
extern "C" __global__ void __launch_bounds__(NTHR)
emd_all(const float* __restrict__ x, const float* __restrict__ y,
        float* __restrict__ out)
{
  __shared__ float  part[RPB * NCK];
  __shared__ double ldsd[16];

  const int tid = threadIdx.x;
  const int bid = blockIdx.x;
  const int gt  = bid * NTHR + tid;
  const int rowBase = bid * RPB;
  unsigned k = 1;

  // EVERY block builds the FULL pack arrays with plain stores (identical
  // values; races are benign). Own-XCD L2 then serves all pack reads with
  // no cross-XCD coherence requirement. d_in is pristine & read-only.
  for (int i = tid; i < N; i += NTHR) {
    float a0 = x[i * 3 + 0], a1 = x[i * 3 + 1], a2 = x[i * 3 + 2];
    g_ws.xpack[i] = make_float4(a0, a1, a2, fmaf(a0, a0, fmaf(a1, a1, a2 * a2)));
    float b0 = y[i * 3 + 0], b1 = y[i * 3 + 1], b2 = y[i * 3 + 2];
    g_ws.ypack[i] = make_float4(b0, b1, b2, fmaf(b0, b0, fmaf(b1, b1, b2 * b2)));
  }
  // potentials init (f=g=0 -> transformed -12), coherent stores, blocks 0..3
  if (gt < N) { cstore(&g_ws.fs[gt], -12.0f); cstore(&g_ws.gs[gt], -12.0f); }
  __syncthreads();

  // eps = 0.02 * mean(C)  (needs only own-block packs; gbar publishes accC)
  pair_sum(rowBase, 0, 0.f, ldsd);
  gbar(k++);
  const float nie2 = -LOG2E /
      (float)(0.02 * cloadd(&g_ws.accC) / ((double)N * (double)N));

  // 300 Gauss-Seidel Sinkhorn iterations
  for (int it = 0; it < 300; ++it) {
    lse_pass(g_ws.xpack, g_ws.ypack, g_ws.gs, g_ws.fs, rowBase, nie2, part);
    gbar(k++);
    lse_pass(g_ws.ypack, g_ws.xpack, g_ws.fs, g_ws.gs, rowBase, nie2, part);
    gbar(k++);
  }

  // EMD = sum_ij 2^(fs_i+gs_j+nie2*C_ij) * C_ij
  pair_sum(rowBase, 1, nie2, ldsd);
  gbar(k++);
  if (gt == 0) out[0] = (float)cloadd(&g_ws.accE);
}

extern "C" void kernel_launch(void* const* d_in, const int* in_sizes, int n_in,
                              void* d_out, int out_size, void* d_ws, size_t ws_size,
                              hipStream_t stream) {
  const float* x = (const float*)d_in[0];
  const float* y = (const float*)d_in[1];
  float* out = (float*)d_out;
  (void)d_ws; (void)ws_size;

  k_init<<<dim3(1), dim3(NBLK), 0, stream>>>();
  emd_all<<<dim3(NBLK), dim3(NTHR), 0, stream>>>(x, y, out);
}